// Round 11
// baseline (524.808 us; speedup 1.0000x reference)
//
#include <hip/hip_runtime.h>
#include <hip/hip_cooperative_groups.h>
#include <stdint.h>

namespace cg = cooperative_groups;

typedef unsigned short u16;
typedef unsigned int   u32;

#define N_NODES  100000
#define N_EDGES  1600000
#define DFEAT    128
#define N_GRAPHS 512

#define NBKT   391    // buckets of 256 nodes (ceil(N/256)); also build_k grid
#define EPB    8192   // edges per block in hist/scatter
#define NBLK_E 196    // ceil(N_EDGES/EPB)
#define LBUF   8192   // per-bucket capacity (mean 4096, sigma ~64)

typedef float f32x4 __attribute__((ext_vector_type(4)));
typedef short s16x8 __attribute__((ext_vector_type(8)));

__device__ __forceinline__ float bflo(u32 u) { return __uint_as_float(u << 16); }
__device__ __forceinline__ float bfhi(u32 u) { return __uint_as_float(u & 0xffff0000u); }
__device__ __forceinline__ u16 f2bf(float f) {
  u32 u = __float_as_uint(f);
  return (u16)((u + 0x7fffu + ((u >> 16) & 1u)) >> 16);   // RNE
}
__device__ __forceinline__ u32 pack2(float f0, float f1) {
  return (u32)f2bf(f0) | ((u32)f2bf(f1) << 16);
}

__device__ __forceinline__ int ld_src(const int* ei, int m, int e) {
  return m ? ei[2 * e] : ei[e];
}
__device__ __forceinline__ int ld_dst(const int* ei, int m, int e) {
  return m ? ei[2 * (N_EDGES + e)] : ei[N_EDGES + e];
}

// block-local int64-vs-int32 detect (odd words of first 64 edge slots all zero <=> int64)
__device__ __forceinline__ int detect_m_block(const int* __restrict__ ei, int* sm) {
  int t = threadIdx.x;
  if (t < 64) {
    int v = ei[2 * t + 1];
    unsigned long long b = __ballot(v != 0);
    if (t == 0) *sm = (b == 0ull) ? 1 : 0;
  }
  __syncthreads();
  return *sm;
}

// ---------------- cooperative graph build: hist -> scatter -> CSR fill ----------------
// grid = NBKT(391) blocks x 256. Phase1: blocks 0..195 histogram (k-major ghist),
// blocks 196..198 W transpose+convert, block 199 flag. Phase2: all blocks compute
// bucket bases (k-major contiguous sums); blocks 0..195 scatter edges into bucket
// regions. Phase3: all 391 blocks finalize CSR (degrees, rowptr, dinv, placement).
__global__ __launch_bounds__(256) void build_k(const int* __restrict__ ei,
                                               int* __restrict__ ghist,
                                               u32* __restrict__ colpk,
                                               int* __restrict__ colarr,
                                               int* __restrict__ rowptr,
                                               float* __restrict__ dinv,
                                               const float* __restrict__ W1,
                                               const float* __restrict__ W2,
                                               const float* __restrict__ W3,
                                               u16* __restrict__ T1,
                                               u16* __restrict__ T2,
                                               u16* __restrict__ T3,
                                               int* __restrict__ flag) {
  cg::grid_group grid = cg::this_grid();
  __shared__ int sm;
  __shared__ int hist[NBKT];
  __shared__ int colsum[NBKT];
  __shared__ int colpre[NBKT];
  __shared__ int cur[NBKT];
  __shared__ int bb[NBKT + 1];
  __shared__ int sc[256];
  __shared__ int fhist[256];
  __shared__ int fcur[256];
  __shared__ int lbuf[LBUF];

  int t = threadIdx.x, b = blockIdx.x;

  // ---------- P1 ----------
  if (b < NBLK_E) {
    int m = detect_m_block(ei, &sm);
    for (int i = t; i < NBKT; i += 256) hist[i] = 0;
    __syncthreads();
    int e0 = b * EPB;
#pragma unroll
    for (int p = 0; p < EPB / 256; p++) {
      int e = e0 + p * 256 + t;
      if (e < N_EDGES) atomicAdd(&hist[ld_dst(ei, m, e) >> 8], 1);
    }
    __syncthreads();
    for (int i = t; i < NBKT; i += 256) ghist[(size_t)i * NBLK_E + b] = hist[i];
  } else if (b < NBLK_E + 3) {
    int r = b - NBLK_E;
    const float* W = (r == 0) ? W1 : (r == 1) ? W2 : W3;
    u16* T         = (r == 0) ? T1 : (r == 1) ? T2 : T3;
    for (int i = t; i < DFEAT * DFEAT; i += 256) {
      int n = i >> 7, k = i & 127;
      T[i] = f2bf(W[k * DFEAT + n]);
    }
  } else if (b == NBLK_E + 3) {
    if (t < 64) {
      int v = ei[2 * t + 1];
      unsigned long long mm = __ballot(v != 0);
      if (t == 0) *flag = (mm == 0ull) ? 1 : 0;
    }
  }
  grid.sync();

  // ---------- P2: bucket bases (all blocks) + scatter (blocks 0..195) ----------
  for (int k = t; k < NBKT; k += 256) {
    const int* row = ghist + (size_t)k * NBLK_E;
    int tot = 0, pre = 0;
    for (int b2 = 0; b2 < NBLK_E; b2++) {
      int v = row[b2];
      tot += v;
      pre += (b2 < b) ? v : 0;
    }
    colsum[k] = tot; colpre[k] = pre;
  }
  __syncthreads();
  // exclusive scan of colsum[NBKT] -> bb[NBKT+1]
  {
    int v0 = colsum[t];
    sc[t] = v0;
    for (int off = 1; off < 256; off <<= 1) {
      __syncthreads(); int add = (t >= off) ? sc[t - off] : 0;
      __syncthreads(); sc[t] += add;
    }
    __syncthreads();
    bb[t] = sc[t] - v0;
    int base256 = sc[255];
    __syncthreads();
    int v1 = (t < NBKT - 256) ? colsum[256 + t] : 0;
    sc[t] = v1;
    for (int off = 1; off < 256; off <<= 1) {
      __syncthreads(); int add = (t >= off) ? sc[t - off] : 0;
      __syncthreads(); sc[t] += add;
    }
    __syncthreads();
    if (t < NBKT - 256) bb[256 + t] = base256 + sc[t] - v1;
    if (t == 0) bb[NBKT] = N_EDGES;
    __syncthreads();
  }
  if (b < NBLK_E) {
    int m = detect_m_block(ei, &sm);
    for (int k = t; k < NBKT; k += 256) cur[k] = bb[k] + colpre[k];
    __syncthreads();
    int e0 = b * EPB;
#pragma unroll
    for (int p = 0; p < EPB / 256; p++) {
      int e = e0 + p * 256 + t;
      if (e < N_EDGES) {
        int d = ld_dst(ei, m, e);
        int s = ld_src(ei, m, e);
        int pos = atomicAdd(&cur[d >> 8], 1);
        colpk[pos] = (u32)s | ((u32)(d & 255) << 24);
      }
    }
  }
  grid.sync();

  // ---------- P3: CSR finalize (all 391 blocks) ----------
  int base = bb[b], end = bb[b + 1], cnt = end - base;
  fhist[t] = 0;
  __syncthreads();
  for (int i = t; i < cnt; i += 256) atomicAdd(&fhist[colpk[base + i] >> 24], 1);
  __syncthreads();
  int c = fhist[t];
  fcur[t] = c;
  for (int off = 1; off < 256; off <<= 1) {
    __syncthreads(); int add = (t >= off) ? fcur[t - off] : 0;
    __syncthreads(); fcur[t] += add;
  }
  __syncthreads();
  int excl = fcur[t] - c;
  int node = b * 256 + t;
  if (node < N_NODES) {
    rowptr[node] = base + excl;
    dinv[node] = rsqrtf((float)(c + 1));      // +1 self-loop
  }
  if (b == NBKT - 1 && t == 0) rowptr[N_NODES] = N_EDGES;
  __syncthreads();
  fcur[t] = excl;
  __syncthreads();
  for (int i = t; i < cnt; i += 256) {
    u32 v = colpk[base + i];
    int slot = atomicAdd(&fcur[v >> 24], 1);
    if (slot < LBUF) lbuf[slot] = (int)(v & 0x00FFFFFFu);
  }
  __syncthreads();
  for (int i = t; i < cnt; i += 256) colarr[base + i] = lbuf[i];
}

// ---------------- MFMA GEMM: Y[r,:] = bf16((X @ W)[r,:] * dinv[r]) ----------------
// 128x128 tile; X input either f32 (converted during staging) or bf16.
#define LP 136   // LDS pitch in ushorts (272B, 16B-aligned rows)

__global__ __launch_bounds__(256, 1) void gemm_scale_k(const void* __restrict__ Xv,
                                                       int x_is_f32,
                                                       const u16* __restrict__ Wt,
                                                       const float* __restrict__ dinv,
                                                       u16* __restrict__ Y, int nrows) {
  __shared__ u16 sX[128 * LP];
  __shared__ u16 sW[128 * LP];
  int tid = threadIdx.x;
  int r0 = blockIdx.x * 128;

  for (int c = tid; c < 2048; c += 256) {
    int row = c >> 4, off = (c & 15) * 8;
    *(uint4*)(&sW[row * LP + off]) = *(const uint4*)(Wt + row * DFEAT + off);
  }
  if (x_is_f32) {
    const float* Xf = (const float*)Xv;
    for (int c = tid; c < 2048; c += 256) {
      int row = c >> 4, off = (c & 15) * 8;
      int grow = r0 + row;
      uint4 o = make_uint4(0, 0, 0, 0);
      if (grow < nrows) {
        const float* px = Xf + (size_t)grow * DFEAT + off;
        float4 v0 = *(const float4*)px;
        float4 v1 = *(const float4*)(px + 4);
        o.x = pack2(v0.x, v0.y); o.y = pack2(v0.z, v0.w);
        o.z = pack2(v1.x, v1.y); o.w = pack2(v1.z, v1.w);
      }
      *(uint4*)(&sX[row * LP + off]) = o;
    }
  } else {
    const u16* Xb = (const u16*)Xv;
    for (int c = tid; c < 2048; c += 256) {
      int row = c >> 4, off = (c & 15) * 8;
      int grow = r0 + row;
      uint4 v = make_uint4(0, 0, 0, 0);
      if (grow < nrows) v = *(const uint4*)(Xb + (size_t)grow * DFEAT + off);
      *(uint4*)(&sX[row * LP + off]) = v;
    }
  }
  __syncthreads();

  int wave = tid >> 6, lane = tid & 63;
  int q = lane >> 4, r = lane & 15;
  int wr0 = wave * 32;

  f32x4 acc[2][8];
#pragma unroll
  for (int m = 0; m < 2; m++)
#pragma unroll
    for (int i = 0; i < 8; i++) acc[m][i] = (f32x4){0.f, 0.f, 0.f, 0.f};

#pragma unroll
  for (int kk = 0; kk < 4; kk++) {
    int k0 = kk * 32;
    s16x8 a0 = *(const s16x8*)(&sX[(wr0 + r) * LP + k0 + q * 8]);
    s16x8 a1 = *(const s16x8*)(&sX[(wr0 + 16 + r) * LP + k0 + q * 8]);
#pragma unroll
    for (int nt = 0; nt < 8; nt++) {
      s16x8 b = *(const s16x8*)(&sW[(nt * 16 + r) * LP + k0 + q * 8]);
      acc[0][nt] = __builtin_amdgcn_mfma_f32_16x16x32_bf16(a0, b, acc[0][nt], 0, 0, 0);
      acc[1][nt] = __builtin_amdgcn_mfma_f32_16x16x32_bf16(a1, b, acc[1][nt], 0, 0, 0);
    }
  }

#pragma unroll
  for (int m = 0; m < 2; m++) {
#pragma unroll
    for (int i = 0; i < 4; i++) {
      int grow = r0 + wr0 + m * 16 + q * 4 + i;
      if (grow < nrows) {
        float dv = dinv[grow];
#pragma unroll
        for (int nt = 0; nt < 8; nt++) {
          Y[(size_t)grow * DFEAT + nt * 16 + r] = f2bf(acc[m][nt][i] * dv);
        }
      }
    }
  }
}

// ---------------- aggregation (bf16 rows, f32 accumulate) — R8's proven 60.5us ----
struct Acc8 {
  float a0, a1, a2, a3, a4, a5, a6, a7;
  __device__ __forceinline__ void add(uint4 v) {
    a0 += bflo(v.x); a1 += bfhi(v.x); a2 += bflo(v.y); a3 += bfhi(v.y);
    a4 += bflo(v.z); a5 += bfhi(v.z); a6 += bflo(v.w); a7 += bfhi(v.w);
  }
};

__global__ __launch_bounds__(256) void agg_k(const u32* __restrict__ HS,
                                             const float* __restrict__ dinv,
                                             const int* __restrict__ rowptr,
                                             const int* __restrict__ colidx,
                                             const float* __restrict__ bias,
                                             u32* __restrict__ OUT, int do_relu) {
  int t = threadIdx.x;
  int node = blockIdx.x * 16 + (t >> 4);   // grid 6250 -> exactly N_NODES
  int fp = t & 15;

  int s = rowptr[node], e = rowptr[node + 1];

  Acc8 A;
  uint4 v = *(const uint4*)(HS + (size_t)node * 64 + fp * 4);   // self row
  A.a0 = bflo(v.x); A.a1 = bfhi(v.x); A.a2 = bflo(v.y); A.a3 = bfhi(v.y);
  A.a4 = bflo(v.z); A.a5 = bfhi(v.z); A.a6 = bflo(v.w); A.a7 = bfhi(v.w);

  int j = s;
  for (; j + 4 <= e; j += 4) {
    int i0 = colidx[j], i1 = colidx[j + 1], i2 = colidx[j + 2], i3 = colidx[j + 3];
    uint4 w0 = *(const uint4*)(HS + (size_t)i0 * 64 + fp * 4);
    uint4 w1 = *(const uint4*)(HS + (size_t)i1 * 64 + fp * 4);
    uint4 w2 = *(const uint4*)(HS + (size_t)i2 * 64 + fp * 4);
    uint4 w3 = *(const uint4*)(HS + (size_t)i3 * 64 + fp * 4);
    A.add(w0); A.add(w1); A.add(w2); A.add(w3);
  }
  for (; j < e; j++) {
    int i0 = colidx[j];
    uint4 w0 = *(const uint4*)(HS + (size_t)i0 * 64 + fp * 4);
    A.add(w0);
  }

  float dv = dinv[node];
  float4 b0 = *(const float4*)(bias + fp * 8);
  float4 b1 = *(const float4*)(bias + fp * 8 + 4);
  float r0 = A.a0 * dv + b0.x, r1 = A.a1 * dv + b0.y;
  float r2 = A.a2 * dv + b0.z, r3 = A.a3 * dv + b0.w;
  float r4 = A.a4 * dv + b1.x, r5 = A.a5 * dv + b1.y;
  float r6 = A.a6 * dv + b1.z, r7 = A.a7 * dv + b1.w;
  if (do_relu) {
    r0 = fmaxf(r0, 0.f); r1 = fmaxf(r1, 0.f); r2 = fmaxf(r2, 0.f); r3 = fmaxf(r3, 0.f);
    r4 = fmaxf(r4, 0.f); r5 = fmaxf(r5, 0.f); r6 = fmaxf(r6, 0.f); r7 = fmaxf(r7, 0.f);
  }
  uint4 o;
  o.x = pack2(r0, r1); o.y = pack2(r2, r3); o.z = pack2(r4, r5); o.w = pack2(r6, r7);
  *(uint4*)(OUT + (size_t)node * 64 + fp * 4) = o;
}

// ---------------- pooling: mean over sorted batch ranges ----------------
__device__ __forceinline__ int lower_bound_i(const int* a, int n, int key, int shift) {
  int lo = 0, hi = n;
  while (lo < hi) {
    int mid = (lo + hi) >> 1;
    if (a[mid << shift] < key) lo = mid + 1; else hi = mid;
  }
  return lo;
}

__global__ __launch_bounds__(256) void pool_k(const u32* __restrict__ H,
                                              const int* __restrict__ batch,
                                              const int* __restrict__ flag,
                                              float* __restrict__ OUT) {
  int g = blockIdx.x;
  int m = *flag;   // 1 if int64 batch
  int lo = lower_bound_i(batch, N_NODES, g, m);
  int hi = lower_bound_i(batch, N_NODES, g + 1, m);
  int cnt = hi - lo;
  int d2 = threadIdx.x & 63;
  int half = threadIdx.x >> 6;
  float a0 = 0.f, a1 = 0.f;
  for (int row = lo + half; row < hi; row += 4) {
    u32 v = H[(size_t)row * 64 + d2];
    a0 += bflo(v); a1 += bfhi(v);
  }
  __shared__ float red0[256], red1[256];
  red0[threadIdx.x] = a0; red1[threadIdx.x] = a1;
  __syncthreads();
  if (threadIdx.x < 64) {
    float s0 = red0[d2] + red0[d2 + 64] + red0[d2 + 128] + red0[d2 + 192];
    float s1 = red1[d2] + red1[d2 + 64] + red1[d2 + 128] + red1[d2 + 192];
    float inv = 1.0f / fmaxf((float)cnt, 1.0f);
    OUT[g * DFEAT + 2 * d2]     = s0 * inv;
    OUT[g * DFEAT + 2 * d2 + 1] = s1 * inv;
  }
}

// ---------------- orchestration (8 dispatches) ----------------

extern "C" void kernel_launch(void* const* d_in, const int* in_sizes, int n_in,
                              void* d_out, int out_size, void* d_ws, size_t ws_size,
                              hipStream_t stream) {
  const float* x   = (const float*)d_in[0];
  const int* ei    = (const int*)d_in[1];
  const int* batch = (const int*)d_in[2];
  const float* W1  = (const float*)d_in[3];
  const float* b1  = (const float*)d_in[4];
  const float* W2  = (const float*)d_in[5];
  const float* b2  = (const float*)d_in[6];
  const float* W3  = (const float*)d_in[7];
  const float* b3  = (const float*)d_in[8];
  float* out = (float*)d_out;

  char* p = (char*)d_ws;
  size_t off = 0;
  auto carve = [&](size_t bytes) -> void* {
    void* q = p + off;
    off = (off + bytes + 255) & ~(size_t)255;
    return q;
  };
  int*   flag   = (int*)carve(256);
  int*   ghist  = (int*)carve((size_t)NBKT * NBLK_E * 4);  // k-major
  int*   rowptr = (int*)carve((N_NODES + 1) * 4);
  float* dinv   = (float*)carve(N_NODES * 4);
  u32*   colpk  = (u32*)carve((size_t)N_EDGES * 4);
  int*   colarr = (int*)carve((size_t)N_EDGES * 4);
  u16*   Wt1    = (u16*)carve(DFEAT * DFEAT * 2);
  u16*   Wt2    = (u16*)carve(DFEAT * DFEAT * 2);
  u16*   Wt3    = (u16*)carve(DFEAT * DFEAT * 2);
  u32*   bufA   = (u32*)carve((size_t)N_NODES * 64 * 4);
  u32*   bufB   = (u32*)carve((size_t)N_NODES * 64 * 4);
  (void)ws_size;

  const int AB = N_NODES / 16;            // 6250
  const int GB = (N_NODES + 127) / 128;   // 782

  // 1: cooperative graph build (hist + W cvt + flag -> scatter -> CSR fill)
  {
    void* kargs[] = {(void*)&ei, (void*)&ghist, (void*)&colpk, (void*)&colarr,
                     (void*)&rowptr, (void*)&dinv, (void*)&W1, (void*)&W2,
                     (void*)&W3, (void*)&Wt1, (void*)&Wt2, (void*)&Wt3,
                     (void*)&flag};
    hipLaunchCooperativeKernel((void*)build_k, dim3(NBKT), dim3(256), kargs, 0, stream);
  }
  // 2-7: per-layer GEMM (dinv-scaled) + aggregation
  gemm_scale_k<<<GB, 256, 0, stream>>>((const void*)x, 1, Wt1, dinv, (u16*)bufA, N_NODES);
  agg_k<<<AB, 256, 0, stream>>>(bufA, dinv, rowptr, colarr, b1, bufB, 1);
  gemm_scale_k<<<GB, 256, 0, stream>>>((const void*)bufB, 0, Wt2, dinv, (u16*)bufA, N_NODES);
  agg_k<<<AB, 256, 0, stream>>>(bufA, dinv, rowptr, colarr, b2, bufB, 1);
  gemm_scale_k<<<GB, 256, 0, stream>>>((const void*)bufB, 0, Wt3, dinv, (u16*)bufA, N_NODES);
  agg_k<<<AB, 256, 0, stream>>>(bufA, dinv, rowptr, colarr, b3, bufB, 0);
  // 8: pooling
  pool_k<<<N_GRAPHS, 256, 0, stream>>>(bufB, batch, flag, out);
}